// Round 15
// baseline (10140.799 us; speedup 1.0000x reference)
//
#include <hip/hip_runtime.h>
#include <math.h>

#define NN 16000
#define NE 256000
#define NG 64
#define HD 128
#define NRAD 96
#define H3 384
#define KD 480   // 2H + H + NRAD

typedef unsigned short u16;
typedef short short8 __attribute__((ext_vector_type(8)));
typedef float f32x4 __attribute__((ext_vector_type(4)));

__device__ __forceinline__ float siluf(float x){ return x / (1.0f + expf(-x)); }

__device__ __forceinline__ float wsum(float v){
#pragma unroll
    for (int o = 32; o > 0; o >>= 1) v += __shfl_xor(v, o, 64);
    return v;
}

// f32 -> bf16 (RNE) and back
__device__ __forceinline__ u16 f2bh(float f){
    unsigned int u = __float_as_uint(f);
    unsigned int r = u + 0x7FFFu + ((u >> 16) & 1u);
    return (u16)(r >> 16);
}
__device__ __forceinline__ float bh2f(u16 h){
    return __uint_as_float((unsigned int)h << 16);
}
__device__ __forceinline__ short8 ld8(const u16* p){ return *(const short8*)p; }

// RNE pack: float4 -> 4 bf16 in uint2
__device__ __forceinline__ uint2 pack4(float4 v){
    uint2 ph;
    ph.x = (unsigned)f2bh(v.x) | ((unsigned)f2bh(v.y) << 16);
    ph.y = (unsigned)f2bh(v.z) | ((unsigned)f2bh(v.w) << 16);
    return ph;
}

// ---------------------------------------------------------------- fill
__global__ void k_fill(float* __restrict__ p, float v, int n){
    int i = blockIdx.x * blockDim.x + threadIdx.x;
    if (i < n) p[i] = v;
}

// weight (K x N row-major f32) -> transposed bf16 plane (N x K), RNE
__global__ void k_wsplit(const float* __restrict__ src, u16* __restrict__ dh, int K, int N){
    int i = blockIdx.x * 256 + threadIdx.x;
    if (i >= K * N) return;
    int n = i / K, k = i - n * K;
    dh[i] = f2bh(src[(size_t)k * N + n]);
}

// ---------------------------------------------------------------- node embeddings
__global__ void k_node_embed(const float* __restrict__ zw, const float* __restrict__ nw,
                             const int* __restrict__ z, float* __restrict__ s, float* __restrict__ sn){
    int n = blockIdx.x, t = threadIdx.x;   // 64 threads
    int zi = z[n];
    const float* a = zw + (size_t)zi * HD;
    const float* b = nw + (size_t)zi * HD;
    float a0 = a[t], a1 = a[t + 64];
    float m  = wsum(a0 + a1) * (1.f / HD);
    float va = wsum((a0 - m)*(a0 - m) + (a1 - m)*(a1 - m)) * (1.f / HD);
    float r  = rsqrtf(va + 1e-5f);
    s[(size_t)n*HD + t]      = (a0 - m) * r;
    s[(size_t)n*HD + 64 + t] = (a1 - m) * r;
    float b0 = b[t], b1 = b[t + 64];
    m  = wsum(b0 + b1) * (1.f / HD);
    va = wsum((b0 - m)*(b0 - m) + (b1 - m)*(b1 - m)) * (1.f / HD);
    r  = rsqrtf(va + 1e-5f);
    sn[(size_t)n*HD + t]      = (b0 - m) * r;
    sn[(size_t)n*HD + 64 + t] = (b1 - m) * r;
}

// ---------------------------------------------------------------- per-row LN -> silu
__global__ void k_ln_silu(const float* __restrict__ x, float* __restrict__ out){
    int n = blockIdx.x, t = threadIdx.x;
    float a0 = x[(size_t)n*HD + t], a1 = x[(size_t)n*HD + 64 + t];
    float m  = wsum(a0 + a1) * (1.f / HD);
    float va = wsum((a0 - m)*(a0 - m) + (a1 - m)*(a1 - m)) * (1.f / HD);
    float r  = rsqrtf(va + 1e-5f);
    out[(size_t)n*HD + t]      = siluf((a0 - m) * r);
    out[(size_t)n*HD + 64 + t] = siluf((a1 - m) * r);
}

// ---------------------------------------------------------------- per-row LN with affine
__global__ void k_ln_aff(const float* __restrict__ x, const float* __restrict__ g,
                         const float* __restrict__ b, float* __restrict__ out){
    int n = blockIdx.x, t = threadIdx.x;
    float a0 = x[(size_t)n*HD + t], a1 = x[(size_t)n*HD + 64 + t];
    float m  = wsum(a0 + a1) * (1.f / HD);
    float va = wsum((a0 - m)*(a0 - m) + (a1 - m)*(a1 - m)) * (1.f / HD);
    float r  = rsqrtf(va + 1e-5f);
    out[(size_t)n*HD + t]      = g[t]      * ((a0 - m) * r) + b[t];
    out[(size_t)n*HD + 64 + t] = g[64 + t] * ((a1 - m) * r) + b[64 + t];
}

// ---------------------------------------------------------------- edge geometry
__global__ void k_edge_geom(const float* __restrict__ pos, const int* __restrict__ ei,
                            float* __restrict__ dist, float* __restrict__ rbnd,
                            float* __restrict__ frame){
    int e = blockIdx.x * blockDim.x + threadIdx.x;
    if (e >= NE) return;
    int si = ei[e], di = ei[NE + e];
    float sx = pos[si*3], sy = pos[si*3+1], sz = pos[si*3+2];
    float dx = pos[di*3], dy = pos[di*3+1], dz = pos[di*3+2];
    float vx = sx - dx, vy = sy - dy, vz = sz - dz;
    float dd = sqrtf(vx*vx + vy*vy + vz*vz);
    dist[e] = dd;
    float rb = (dd < 6.0f) ? 0.5f * (cosf(dd * 0.5235987755982988f) + 1.0f) : 0.0f;
    rbnd[e] = rb;
    float inv = 1.0f / dd;
    float ux = vx*inv, uy = vy*inv, uz = vz*inv;
    float cx = sy*dz - sz*dy, cy = sz*dx - sx*dz, cz = sx*dy - sy*dx;
    float cn = sqrtf(cx*cx + cy*cy + cz*cz) + 1e-10f;
    cx /= cn; cy /= cn; cz /= cn;
    float wx = uy*cz - uz*cy, wy = uz*cx - ux*cz, wz = ux*cy - uy*cx;
    frame[(0*3+0)*NE + e] = ux; frame[(1*3+0)*NE + e] = uy; frame[(2*3+0)*NE + e] = uz;
    frame[(0*3+1)*NE + e] = cx; frame[(1*3+1)*NE + e] = cy; frame[(2*3+1)*NE + e] = cz;
    frame[(0*3+2)*NE + e] = wx; frame[(1*3+2)*NE + e] = wy; frame[(2*3+2)*NE + e] = wz;
}

// ---------------------------------------------------------------- rbf chunk (f32, stride KD)
__global__ void k_rbf(const float* __restrict__ dist, const float* __restrict__ rbnd,
                      float* __restrict__ base, int e0, int ec){
    int idx = blockIdx.x * 256 + threadIdx.x;
    int e = idx / NRAD;
    if (e >= ec) return;
    int k = idx - e * NRAD;
    int eg = e0 + e;
    float start = expf(-6.0f);
    float mean  = start + (1.0f - start) * ((float)k / 95.0f);
    float c     = (2.0f / 96.0f) * (1.0f - start);
    float betas = 1.0f / (c * c);
    float t = expf(-dist[eg]) - mean;
    base[(size_t)e * KD + k] = rbnd[eg] * expf(-betas * t * t);
}

// ---------------------------------------------------------------- bf16 MFMA GEMM
// C(M,N) = epi(A(M,K,lda f32) @ B); A converted RNE bf16 in-kernel, B bf16 plane (N x K).
// BM=128, BN=64, BK=32; 256 thr = 4 waves. ~2^-9 relative error per operand.
__global__ __launch_bounds__(256)
void mgemm(const float* __restrict__ A, int lda,
           const u16* __restrict__ Bhg, int K,
           const float* __restrict__ bias, int act,
           float* __restrict__ C, int ldc,
           int M, int Nn,
           const float* __restrict__ row_scale,
           const float* __restrict__ mulC, int ldm){
    __shared__ u16 Ah[128*40];
    __shared__ u16 Bh[64*40];
    int tid = threadIdx.x;
    int w = tid >> 6, l = tid & 63;
    int row0 = blockIdx.x * 128, col0 = blockIdx.y * 64;
    f32x4 acc[2][4] = {};
    const int r16 = l & 15, kb = (l >> 4) * 8;

    for (int k0 = 0; k0 < K; k0 += 32){
        if (k0) __syncthreads();
#pragma unroll
        for (int i = 0; i < 4; i++){
            int f = tid + i * 256;
            int r = f >> 3, kq = (f & 7) * 4;
            const float4 v = *(const float4*)(A + (size_t)(row0 + r) * lda + k0 + kq);
            *(uint2*)&Ah[r*40 + kq] = pack4(v);
        }
        {
            int bn = tid >> 2, kq = (tid & 3) * 8;
            const size_t gb = (size_t)(col0 + bn) * K + k0 + kq;
            *(short8*)&Bh[bn*40 + kq] = ld8(Bhg + gb);
        }
        __syncthreads();
        short8 ah0 = *(const short8*)&Ah[(w*32      + r16)*40 + kb];
        short8 ah1 = *(const short8*)&Ah[(w*32 + 16 + r16)*40 + kb];
#pragma unroll
        for (int nf = 0; nf < 4; nf++){
            short8 bhv = *(const short8*)&Bh[(nf*16 + r16)*40 + kb];
            acc[0][nf] = __builtin_amdgcn_mfma_f32_16x16x32_bf16(ah0, bhv, acc[0][nf], 0, 0, 0);
            acc[1][nf] = __builtin_amdgcn_mfma_f32_16x16x32_bf16(ah1, bhv, acc[1][nf], 0, 0, 0);
        }
    }
    int rq = (l >> 4) * 4;
#pragma unroll
    for (int mf = 0; mf < 2; mf++){
#pragma unroll
        for (int nf = 0; nf < 4; nf++){
            int n = col0 + nf*16 + r16;
            float bz = bias ? bias[n] : 0.0f;
#pragma unroll
            for (int reg = 0; reg < 4; reg++){
                int m = row0 + w*32 + mf*16 + rq + reg;
                float v = acc[mf][nf][reg] + bz;
                if (act) v = siluf(v);
                if (row_scale) v *= row_scale[m];
                if (mulC) v *= mulC[(size_t)m * ldm + n];
                C[(size_t)m * ldc + n] = v;
            }
        }
    }
}

// ---------------------------------------------------------------- fused rw-GEMM + dw2-GEMM + scatter (all bf16)
__global__ __launch_bounds__(256)
void dw2s(const float* __restrict__ hb,
          const float* __restrict__ ewrbf,
          const u16* __restrict__ B1h,
          const u16* __restrict__ B2h,
          const float* __restrict__ rb, const float* __restrict__ db2,
          const float* __restrict__ xh, const float* __restrict__ vec,
          const float* __restrict__ frame, const int* __restrict__ ei,
          float* __restrict__ s, float* __restrict__ vec_acc, int e0){
    __shared__ u16 Ah[128*40];
    __shared__ u16 Bh[64*40];
    int tid = threadIdx.x;
    int w = tid >> 6, l = tid & 63;
    int row0 = blockIdx.x * 128, col0 = blockIdx.y * 64;
    const int r16 = l & 15, kb = (l >> 4) * 8;
    f32x4 acc1[2][4] = {}, acc2[2][4] = {};

    // phase 2: acc2 = rbf @ rw (K=96, A stride KD)
    for (int k0 = 0; k0 < 96; k0 += 32){
        if (k0) __syncthreads();
#pragma unroll
        for (int i = 0; i < 4; i++){
            int f = tid + i * 256;
            int r = f >> 3, kq = (f & 7) * 4;
            const float4 v = *(const float4*)(ewrbf + (size_t)(row0 + r) * KD + k0 + kq);
            *(uint2*)&Ah[r*40 + kq] = pack4(v);
        }
        {
            int bn = tid >> 2, kq = (tid & 3) * 8;
            const size_t gb = (size_t)(col0 + bn) * 96 + k0 + kq;
            *(short8*)&Bh[bn*40 + kq] = ld8(B2h + gb);
        }
        __syncthreads();
        short8 ah0 = *(const short8*)&Ah[(w*32      + r16)*40 + kb];
        short8 ah1 = *(const short8*)&Ah[(w*32 + 16 + r16)*40 + kb];
#pragma unroll
        for (int nf = 0; nf < 4; nf++){
            short8 bhv = *(const short8*)&Bh[(nf*16 + r16)*40 + kb];
            acc2[0][nf] = __builtin_amdgcn_mfma_f32_16x16x32_bf16(ah0, bhv, acc2[0][nf], 0, 0, 0);
            acc2[1][nf] = __builtin_amdgcn_mfma_f32_16x16x32_bf16(ah1, bhv, acc2[1][nf], 0, 0, 0);
        }
    }
    // phase 1: acc1 = hbuf @ dw2 (K=384, A stride H3)
    for (int k0 = 0; k0 < H3; k0 += 32){
        __syncthreads();
#pragma unroll
        for (int i = 0; i < 4; i++){
            int f = tid + i * 256;
            int r = f >> 3, kq = (f & 7) * 4;
            const float4 v = *(const float4*)(hb + (size_t)(row0 + r) * H3 + k0 + kq);
            *(uint2*)&Ah[r*40 + kq] = pack4(v);
        }
        {
            int bn = tid >> 2, kq = (tid & 3) * 8;
            const size_t gb = (size_t)(col0 + bn) * H3 + k0 + kq;
            *(short8*)&Bh[bn*40 + kq] = ld8(B1h + gb);
        }
        __syncthreads();
        short8 ah0 = *(const short8*)&Ah[(w*32      + r16)*40 + kb];
        short8 ah1 = *(const short8*)&Ah[(w*32 + 16 + r16)*40 + kb];
#pragma unroll
        for (int nf = 0; nf < 4; nf++){
            short8 bhv = *(const short8*)&Bh[(nf*16 + r16)*40 + kb];
            acc1[0][nf] = __builtin_amdgcn_mfma_f32_16x16x32_bf16(ah0, bhv, acc1[0][nf], 0, 0, 0);
            acc1[1][nf] = __builtin_amdgcn_mfma_f32_16x16x32_bf16(ah1, bhv, acc1[1][nf], 0, 0, 0);
        }
    }
    // epilogue: rbfh -> scatter
    int rq = (l >> 4) * 4;
    int br = col0 >> 7;          // 0,1,2 (uniform per block)
    int ho = col0 & 127;         // 0 or 64
#pragma unroll
    for (int mf = 0; mf < 2; mf++){
#pragma unroll
        for (int reg = 0; reg < 4; reg++){
            int m  = row0 + w*32 + mf*16 + rq + reg;
            int eg = e0 + m;
            int si = ei[eg], di = ei[NE + eg];
            float df0 = 0.f, df1 = 0.f, df2 = 0.f;
            if (br == 2){
                df0 = frame[0*NE + eg];
                df1 = frame[3*NE + eg];
                df2 = frame[6*NE + eg];
            }
#pragma unroll
            for (int nf = 0; nf < 4; nf++){
                int n = col0 + nf*16 + r16;
                int h = ho + nf*16 + r16;
                float v  = (acc2[mf][nf][reg] + rb[n]) * (acc1[mf][nf][reg] + db2[n]);
                float xv = xh[(size_t)si * H3 + n];
                if (br == 0){
                    atomicAdd(&s[(size_t)di * HD + h], xv * v);
                } else if (br == 1){
                    float m2 = xv * v * 0.5773502691896258f;
                    size_t sb = (size_t)si * H3, db = (size_t)di * H3;
#pragma unroll
                    for (int c = 0; c < 3; c++)
                        atomicAdd(&vec_acc[db + c*HD + h],
                                  vec[sb + c*HD + h] * m2 * 0.08838834764831845f);
                } else {
                    float m3 = xv * v * 0.08838834764831845f;
                    size_t db = (size_t)di * H3;
                    atomicAdd(&vec_acc[db + 0*HD + h], m3 * df0);
                    atomicAdd(&vec_acc[db + 1*HD + h], m3 * df1);
                    atomicAdd(&vec_acc[db + 2*HD + h], m3 * df2);
                }
            }
        }
    }
}

struct WT { u16* h; };

static void gemm(hipStream_t st, const float* A, int lda, WT B,
                 const float* bias, float* C, int ldc, size_t M, int K, int Nn,
                 int act, const float* rs, const float* mul, int ldm){
    dim3 g((unsigned)(M / 128), (unsigned)(Nn / 64)), b(256);
    mgemm<<<g, b, 0, st>>>(A, lda, B.h, K, bias, act, C, ldc, (int)M, Nn, rs, mul, ldm);
}

// ---------------------------------------------------------------- s[dst] += rh * sn[src]
__global__ void k_scatter_s(const float* __restrict__ rh, const float* __restrict__ sn,
                            const int* __restrict__ ei, float* __restrict__ s, int e0, int ec){
    int idx = blockIdx.x * 256 + threadIdx.x;
    int e = idx >> 7, h = idx & 127;
    if (e >= ec) return;
    int eg = e0 + e;
    int si = ei[eg], di = ei[NE + eg];
    atomicAdd(&s[(size_t)di * HD + h], rh[(size_t)e * KD + h] * sn[(size_t)si * HD + h]);
}

// ---------------------------------------------------------------- S_ij[dst,c,h] += rh*diff_c*s1[src,h]
__global__ void k_scatter_msgv(const float* __restrict__ rh, const float* __restrict__ s1,
                               const float* __restrict__ frame, const int* __restrict__ ei,
                               float* __restrict__ S_ij, int e0, int ec){
    int idx = blockIdx.x * 256 + threadIdx.x;
    int e = idx >> 7, h = idx & 127;
    if (e >= ec) return;
    int eg = e0 + e;
    int si = ei[eg], di = ei[NE + eg];
    float mv = rh[(size_t)e * KD + h] * s1[(size_t)si * HD + h];
    size_t db = (size_t)di * H3;
#pragma unroll
    for (int c = 0; c < 3; c++){
        float df = frame[(c*3 + 0) * NE + eg];
        atomicAdd(&S_ij[db + c * HD + h], mv * df);
    }
}

// ---------------------------------------------------------------- scalarize -> base[:,0:256]
__global__ void k_scalarize(const float* __restrict__ S_ij, const float* __restrict__ frame,
                            const float* __restrict__ rbnd, const int* __restrict__ ei,
                            const float* __restrict__ w1, const float* __restrict__ b1,
                            const float* __restrict__ w2, const float* __restrict__ b2v,
                            float* __restrict__ base, int e0){
    int e = blockIdx.x, h = threadIdx.x;   // 128 threads
    int eg = e0 + e;
    int si = ei[eg], di = ei[NE + eg];
    float fr[9];
#pragma unroll
    for (int i = 0; i < 9; i++) fr[i] = frame[i * NE + eg];
    float rb = rbnd[eg];
    float b2 = b2v[0];
#pragma unroll
    for (int g = 0; g < 2; g++){
        int node = g ? di : si;
        float S0 = S_ij[(size_t)node * H3 + h];
        float S1 = S_ij[(size_t)node * H3 + 128 + h];
        float S2 = S_ij[(size_t)node * H3 + 256 + h];
        float p0 = fr[0]*S0 + fr[3]*S1 + fr[6]*S2;
        float p1 = fabsf(fr[1]*S0 + fr[4]*S1 + fr[7]*S2);
        float p2 = fr[2]*S0 + fr[5]*S1 + fr[8]*S2;
        float o = b2 + p0;
#pragma unroll
        for (int j = 0; j < 32; j++){
            float hh = siluf(p0 * w1[j] + p1 * w1[32 + j] + p2 * w1[64 + j] + b1[j]);
            o += hh * w2[j];
        }
        base[(size_t)e * KD + g * 128 + h] = o * rb;
    }
}

__global__ void k_scale_s(float* __restrict__ s){
    int i = blockIdx.x * 256 + threadIdx.x;
    s[i] *= 0.7071067811865476f;
}

__global__ void k_vec_add(float* __restrict__ vec, const float* __restrict__ vec_acc){
    int i = blockIdx.x * 256 + threadIdx.x;
    vec[i] += vec_acc[i];
}

// ---------------------------------------------------------------- v-features
__global__ void k_vfeat(const float* __restrict__ vp, const float* __restrict__ s,
                        float* __restrict__ t256, float* __restrict__ vdot){
    int idx = blockIdx.x * 256 + threadIdx.x;
    int n = idx >> 7, h = idx & 127;
    float a = 0.f, b = 0.f;
#pragma unroll
    for (int c = 0; c < 3; c++){
        float v1 = vp[(size_t)(n*3 + c) * 256 + h];
        float v2 = vp[(size_t)(n*3 + c) * 256 + 128 + h];
        a += v1 * v1;
        b += v1 * v2;
    }
    t256[(size_t)n * 256 + 128 + h] = sqrtf(a + 1e-10f);
    vdot[idx] = b * 0.08838834764831845f;
    t256[(size_t)n * 256 + h] = s[idx];
}

__global__ void k_upd_s(float* __restrict__ s, const float* __restrict__ xvh,
                        const float* __restrict__ vdot){
    int idx = blockIdx.x * 256 + threadIdx.x;
    int n = idx >> 7, h = idx & 127;
    s[idx] += (xvh[(size_t)n * H3 + h] + xvh[(size_t)n * H3 + 128 + h] + vdot[idx]) * 0.7071067811865476f;
}

__global__ void k_upd_vec(float* __restrict__ vec, const float* __restrict__ xvh,
                          const float* __restrict__ vp){
    int idx = blockIdx.x * 256 + threadIdx.x;
    int n = idx / H3;
    int r = idx - n * H3;
    int c = r >> 7, h = r & 127;
    vec[idx] += xvh[(size_t)n * H3 + 256 + h] * vp[(size_t)(n*3 + c) * 256 + 128 + h];
}

// ---------------------------------------------------------------- final readout
__global__ void k_final(const float* __restrict__ s, const float* __restrict__ lw,
                        const float* __restrict__ lb, const int* __restrict__ batch,
                        float* __restrict__ out){
    int n = blockIdx.x, t = threadIdx.x;   // 64 threads
    float v = s[(size_t)n * HD + t] * lw[t] + s[(size_t)n * HD + 64 + t] * lw[64 + t];
    v = wsum(v);
    if (t == 0) atomicAdd(&out[batch[n]], v + lb[0]);
}

// ================================================================ host
extern "C" void kernel_launch(void* const* d_in, const int* in_sizes, int n_in,
                              void* d_out, int out_size, void* d_ws, size_t ws_size,
                              hipStream_t stream){
    const float* pos      = (const float*)d_in[0];
    const float* z_emb_w  = (const float*)d_in[1];
    const float* ne_emb_w = (const float*)d_in[2];
    const float* rl_w1    = (const float*)d_in[3];
    const float* rl_b1    = (const float*)d_in[4];
    const float* rl_w2    = (const float*)d_in[5];
    const float* rl_b2    = (const float*)d_in[6];
    const float* sv_w     = (const float*)d_in[7];
    const float* sv_b     = (const float*)d_in[8];
    const float* lin_w1   = (const float*)d_in[9];
    const float* lin_b1   = (const float*)d_in[10];
    const float* lin_w2   = (const float*)d_in[11];
    const float* lin_b2   = (const float*)d_in[12];
    const float* mp_ln_g  = (const float*)d_in[13];
    const float* mp_ln_b  = (const float*)d_in[14];
    const float* mp_xw1   = (const float*)d_in[15];
    const float* mp_xb1   = (const float*)d_in[16];
    const float* mp_xw2   = (const float*)d_in[17];
    const float* mp_xb2   = (const float*)d_in[18];
    const float* mp_rw    = (const float*)d_in[19];
    const float* mp_rb    = (const float*)d_in[20];
    const float* mp_dw1   = (const float*)d_in[21];
    const float* mp_db1   = (const float*)d_in[22];
    const float* mp_dw2   = (const float*)d_in[23];
    const float* mp_db2   = (const float*)d_in[24];
    const float* ft_vw    = (const float*)d_in[25];
    const float* ft_xw1   = (const float*)d_in[26];
    const float* ft_xb1   = (const float*)d_in[27];
    const float* ft_xw2   = (const float*)d_in[28];
    const float* ft_xb2   = (const float*)d_in[29];
    const float* last_w   = (const float*)d_in[30];
    const float* last_b   = (const float*)d_in[31];
    const int*   z        = (const int*)d_in[32];
    const int*   ei       = (const int*)d_in[33];
    const int*   batch    = (const int*)d_in[34];
    float* out = (float*)d_out;
    (void)in_sizes; (void)n_in; (void)out_size;

    float* ws = (float*)d_ws;
    size_t off = 0;
    auto alloc = [&](size_t nf){ float* p = ws + off; off += (nf + 63) & ~(size_t)63; return p; };

    // ---- fixed node/geometry buffers
    float* s       = alloc((size_t)NN * HD);
    float* sn      = alloc((size_t)NN * HD);
    float* s1      = alloc((size_t)NN * HD);
    float* tA      = alloc((size_t)NN * HD);
    float* vdot    = alloc((size_t)NN * HD);
    float* vec     = alloc((size_t)NN * H3);
    float* vec_acc = alloc((size_t)NN * H3);
    float* S_ij    = alloc((size_t)NN * H3);
    float* xh      = alloc((size_t)NN * H3);
    float* vp      = alloc((size_t)NN * 3 * 256);
    float* dist    = alloc((size_t)NE);
    float* rbnd    = alloc((size_t)NE);
    float* frame   = alloc((size_t)NE * 9);
    float* t256    = sn;   // alias: (N,256) over sn+s1 (layer phase only; sn/s1 prologue-only)

    // ---- weight bf16 plane arena (transposed)
    const size_t WELEMS = 45056 + 2 * 548864;
    u16* wcur = (u16*)alloc((WELEMS + 1) / 2);
    auto wsplit = [&](const float* src, int K, int N)->WT{
        WT r; r.h = wcur; wcur += (size_t)K * N;
        k_wsplit<<<(unsigned)(((size_t)K * N + 255) / 256), 256, 0, stream>>>(src, r.h, K, N);
        return r;
    };
    WT W_rl1 = wsplit(rl_w1, NRAD, HD);
    WT W_rl2 = wsplit(rl_w2, HD, HD);
    WT W_sv  = wsplit(sv_w, HD, HD);
    WT W_xw1[2], W_xw2[2], W_rw[2], W_dw1[2], W_dw2[2], W_vw[2], W_fx1[2], W_fx2[2];
    for (int l = 0; l < 2; l++){
        W_xw1[l] = wsplit(mp_xw1 + (size_t)l * HD * HD, HD, HD);
        W_xw2[l] = wsplit(mp_xw2 + (size_t)l * HD * H3, HD, H3);
        W_rw[l]  = wsplit(mp_rw  + (size_t)l * NRAD * H3, NRAD, H3);
        W_dw1[l] = wsplit(mp_dw1 + (size_t)l * KD * H3, KD, H3);
        W_dw2[l] = wsplit(mp_dw2 + (size_t)l * H3 * H3, H3, H3);
        W_vw[l]  = wsplit(ft_vw  + (size_t)l * HD * 256, HD, 256);
        W_fx1[l] = wsplit(ft_xw1 + (size_t)l * 256 * HD, 256, HD);
        W_fx2[l] = wsplit(ft_xw2 + (size_t)l * HD * H3, HD, H3);
    }

    // ---- adaptive edge scratch (CE multiple of 128; L3-residency cap)
    size_t availF = ws_size / sizeof(float);
    size_t rem = (availF > off + 1024) ? (availF - off - 1024) : 0;
    const size_t EWF = (size_t)NE * KD;
    bool persist;
    size_t CE;
    float* ew  = nullptr;
    float* ewc = nullptr;
    if (rem >= EWF + 128 * 384 + 256){
        persist = true;
        ew = alloc(EWF);
        rem = availF - off - 1024;
        size_t ce = rem / (size_t)H3;
        CE = ce & ~(size_t)127;
        if (CE < 128) CE = 128;
        if (CE > NE) CE = NE;
    } else {
        persist = false;
        size_t ce = rem / ((size_t)KD + (size_t)H3);
        CE = ce & ~(size_t)127;
        if (CE < 128) CE = 128;
        if (CE > NE) CE = NE;
    }
    if (CE > 32768) CE = 32768;
    if (!persist) ewc = alloc(CE * KD);
    float* hbuf = alloc(CE * (size_t)H3);

    auto build_rh = [&](size_t e0, size_t ec, float* base){
        k_rbf<<<(unsigned)((ec * NRAD) / 256), 256, 0, stream>>>(dist, rbnd, base + 384, (int)e0, (int)ec);
        gemm(stream, base + 384, KD, W_rl1, rl_b1, hbuf, HD, ec, NRAD, HD, 1, nullptr, nullptr, 0);
        gemm(stream, hbuf, HD, W_rl2, rl_b2, base + 256, KD, ec, HD, HD, 0, rbnd + e0, nullptr, 0);
    };

    // ---- prologue
    k_fill<<<1, 64, 0, stream>>>(out, 0.f, NG);
    k_node_embed<<<NN, 64, 0, stream>>>(z_emb_w, ne_emb_w, z, s, sn);
    k_edge_geom<<<NE / 256, 256, 0, stream>>>(pos, ei, dist, rbnd, frame);

    for (size_t e0 = 0; e0 < NE; e0 += CE){
        size_t ec = (NE - e0 < CE) ? (NE - e0) : CE;
        float* base = persist ? (ew + e0 * KD) : ewc;
        build_rh(e0, ec, base);
        k_scatter_s<<<(unsigned)((ec * HD) / 256), 256, 0, stream>>>(base + 256, sn, ei, s, (int)e0, (int)ec);
    }

    gemm(stream, s, HD, W_sv, sv_b, tA, HD, NN, HD, HD, 0, nullptr, nullptr, 0);
    k_ln_silu<<<NN, 64, 0, stream>>>(tA, s1);

    k_fill<<<(NN * H3) / 256, 256, 0, stream>>>(S_ij, 0.f, NN * H3);
    for (size_t e0 = 0; e0 < NE; e0 += CE){
        size_t ec = (NE - e0 < CE) ? (NE - e0) : CE;
        float* base = persist ? (ew + e0 * KD) : ewc;
        if (!persist) build_rh(e0, ec, base);
        k_scatter_msgv<<<(unsigned)((ec * HD) / 256), 256, 0, stream>>>(base + 256, s1, frame, ei, S_ij, (int)e0, (int)ec);
    }

    if (persist)
        k_scalarize<<<NE, 128, 0, stream>>>(S_ij, frame, rbnd, ei, lin_w1, lin_b1, lin_w2, lin_b2, ew, 0);

    k_fill<<<(NN * H3) / 256, 256, 0, stream>>>(vec, 0.f, NN * H3);

    // ---- layer loop
    for (int l = 0; l < 2; l++){
        k_ln_aff<<<NN, 64, 0, stream>>>(s, mp_ln_g + l * HD, mp_ln_b + l * HD, tA);
        gemm(stream, tA, HD, W_xw1[l], mp_xb1 + l * HD, vdot, HD, NN, HD, HD, 1, nullptr, nullptr, 0);
        gemm(stream, vdot, HD, W_xw2[l], mp_xb2 + l * H3, xh, H3, NN, HD, H3, 0, nullptr, nullptr, 0);

        k_fill<<<(NN * H3) / 256, 256, 0, stream>>>(vec_acc, 0.f, NN * H3);

        for (size_t e0 = 0; e0 < NE; e0 += CE){
            size_t ec = (NE - e0 < CE) ? (NE - e0) : CE;
            float* base = persist ? (ew + e0 * KD) : ewc;
            if (!persist){
                build_rh(e0, ec, base);
                k_scalarize<<<(unsigned)ec, 128, 0, stream>>>(S_ij, frame, rbnd, ei, lin_w1, lin_b1, lin_w2, lin_b2, base, (int)e0);
            }
            gemm(stream, base, KD, W_dw1[l], mp_db1 + l * H3, hbuf, H3, ec, KD, H3, 1, nullptr, nullptr, 0);
            dim3 g((unsigned)(ec / 128), 6);
            dw2s<<<g, 256, 0, stream>>>(hbuf, base + 384,
                                        W_dw2[l].h, W_rw[l].h,
                                        mp_rb + l * H3, mp_db2 + l * H3,
                                        xh, vec, frame, ei, s, vec_acc, (int)e0);
        }
        k_scale_s<<<(NN * HD) / 256, 256, 0, stream>>>(s);
        k_vec_add<<<(NN * H3) / 256, 256, 0, stream>>>(vec, vec_acc);

        gemm(stream, vec, HD, W_vw[l], nullptr, vp, 256, (size_t)NN * 3, HD, 256, 0, nullptr, nullptr, 0);
        k_vfeat<<<(NN * HD) / 256, 256, 0, stream>>>(vp, s, t256, vdot);

        gemm(stream, t256, 256, W_fx1[l], ft_xb1 + l * HD, tA, HD, NN, 256, HD, 1, nullptr, nullptr, 0);
        gemm(stream, tA, HD, W_fx2[l], ft_xb2 + l * H3, xh, H3, NN, HD, H3, 0, nullptr, nullptr, 0);

        k_upd_s<<<(NN * HD) / 256, 256, 0, stream>>>(s, xh, vdot);
        k_upd_vec<<<(NN * H3) / 256, 256, 0, stream>>>(vec, xh, vp);
    }

    // ---- readout
    k_final<<<NN, 64, 0, stream>>>(s, last_w, last_b, batch, out);
}

// Round 16
// 10057.675 us; speedup vs baseline: 1.0083x; 1.0083x over previous
//
#include <hip/hip_runtime.h>
#include <math.h>

#define NN 16000
#define NE 256000
#define NG 64
#define HD 128
#define NRAD 96
#define H3 384
#define KD 480   // 2H + H + NRAD

typedef unsigned short u16;
typedef short short8 __attribute__((ext_vector_type(8)));
typedef float f32x4 __attribute__((ext_vector_type(4)));

__device__ __forceinline__ float siluf(float x){ return x / (1.0f + expf(-x)); }

__device__ __forceinline__ float wsum(float v){
#pragma unroll
    for (int o = 32; o > 0; o >>= 1) v += __shfl_xor(v, o, 64);
    return v;
}

// f32 -> bf16 (RNE) and back
__device__ __forceinline__ u16 f2bh(float f){
    unsigned int u = __float_as_uint(f);
    unsigned int r = u + 0x7FFFu + ((u >> 16) & 1u);
    return (u16)(r >> 16);
}
__device__ __forceinline__ float bh2f(u16 h){
    return __uint_as_float((unsigned int)h << 16);
}
__device__ __forceinline__ short8 ld8(const u16* p){ return *(const short8*)p; }

// fast truncation split: float4 -> packed hi (uint2) + lo (uint2) bf16 pairs.
__device__ __forceinline__ void split4(float4 v, uint2& ph, uint2& pl){
    unsigned ux = __float_as_uint(v.x), uy = __float_as_uint(v.y);
    unsigned uz = __float_as_uint(v.z), uw = __float_as_uint(v.w);
    ph.x = __builtin_amdgcn_perm(uy, ux, 0x07060302u);
    ph.y = __builtin_amdgcn_perm(uw, uz, 0x07060302u);
    float lx = v.x - __uint_as_float(ux & 0xFFFF0000u);
    float ly = v.y - __uint_as_float(uy & 0xFFFF0000u);
    float lz = v.z - __uint_as_float(uz & 0xFFFF0000u);
    float lw = v.w - __uint_as_float(uw & 0xFFFF0000u);
    pl.x = __builtin_amdgcn_perm(__float_as_uint(ly), __float_as_uint(lx), 0x07060302u);
    pl.y = __builtin_amdgcn_perm(__float_as_uint(lw), __float_as_uint(lz), 0x07060302u);
}

// ---------------------------------------------------------------- fill
__global__ void k_fill(float* __restrict__ p, float v, int n){
    int i = blockIdx.x * blockDim.x + threadIdx.x;
    if (i < n) p[i] = v;
}

// weight (K x N row-major f32) -> transposed bf16 plane (N x K), RNE
__global__ void k_wsplit(const float* __restrict__ src, u16* __restrict__ dh, int K, int N){
    int i = blockIdx.x * 256 + threadIdx.x;
    if (i >= K * N) return;
    int n = i / K, k = i - n * K;
    dh[i] = f2bh(src[(size_t)k * N + n]);
}

// ---------------------------------------------------------------- node embeddings
__global__ void k_node_embed(const float* __restrict__ zw, const float* __restrict__ nw,
                             const int* __restrict__ z, float* __restrict__ s, float* __restrict__ sn){
    int n = blockIdx.x, t = threadIdx.x;   // 64 threads
    int zi = z[n];
    const float* a = zw + (size_t)zi * HD;
    const float* b = nw + (size_t)zi * HD;
    float a0 = a[t], a1 = a[t + 64];
    float m  = wsum(a0 + a1) * (1.f / HD);
    float va = wsum((a0 - m)*(a0 - m) + (a1 - m)*(a1 - m)) * (1.f / HD);
    float r  = rsqrtf(va + 1e-5f);
    s[(size_t)n*HD + t]      = (a0 - m) * r;
    s[(size_t)n*HD + 64 + t] = (a1 - m) * r;
    float b0 = b[t], b1 = b[t + 64];
    m  = wsum(b0 + b1) * (1.f / HD);
    va = wsum((b0 - m)*(b0 - m) + (b1 - m)*(b1 - m)) * (1.f / HD);
    r  = rsqrtf(va + 1e-5f);
    sn[(size_t)n*HD + t]      = (b0 - m) * r;
    sn[(size_t)n*HD + 64 + t] = (b1 - m) * r;
}

// ---------------------------------------------------------------- per-row LN -> silu
__global__ void k_ln_silu(const float* __restrict__ x, float* __restrict__ out){
    int n = blockIdx.x, t = threadIdx.x;
    float a0 = x[(size_t)n*HD + t], a1 = x[(size_t)n*HD + 64 + t];
    float m  = wsum(a0 + a1) * (1.f / HD);
    float va = wsum((a0 - m)*(a0 - m) + (a1 - m)*(a1 - m)) * (1.f / HD);
    float r  = rsqrtf(va + 1e-5f);
    out[(size_t)n*HD + t]      = siluf((a0 - m) * r);
    out[(size_t)n*HD + 64 + t] = siluf((a1 - m) * r);
}

// ---------------------------------------------------------------- per-row LN with affine
__global__ void k_ln_aff(const float* __restrict__ x, const float* __restrict__ g,
                         const float* __restrict__ b, float* __restrict__ out){
    int n = blockIdx.x, t = threadIdx.x;
    float a0 = x[(size_t)n*HD + t], a1 = x[(size_t)n*HD + 64 + t];
    float m  = wsum(a0 + a1) * (1.f / HD);
    float va = wsum((a0 - m)*(a0 - m) + (a1 - m)*(a1 - m)) * (1.f / HD);
    float r  = rsqrtf(va + 1e-5f);
    out[(size_t)n*HD + t]      = g[t]      * ((a0 - m) * r) + b[t];
    out[(size_t)n*HD + 64 + t] = g[64 + t] * ((a1 - m) * r) + b[64 + t];
}

// ---------------------------------------------------------------- edge geometry
__global__ void k_edge_geom(const float* __restrict__ pos, const int* __restrict__ ei,
                            float* __restrict__ dist, float* __restrict__ rbnd,
                            float* __restrict__ frame){
    int e = blockIdx.x * blockDim.x + threadIdx.x;
    if (e >= NE) return;
    int si = ei[e], di = ei[NE + e];
    float sx = pos[si*3], sy = pos[si*3+1], sz = pos[si*3+2];
    float dx = pos[di*3], dy = pos[di*3+1], dz = pos[di*3+2];
    float vx = sx - dx, vy = sy - dy, vz = sz - dz;
    float dd = sqrtf(vx*vx + vy*vy + vz*vz);
    dist[e] = dd;
    float rb = (dd < 6.0f) ? 0.5f * (cosf(dd * 0.5235987755982988f) + 1.0f) : 0.0f;
    rbnd[e] = rb;
    float inv = 1.0f / dd;
    float ux = vx*inv, uy = vy*inv, uz = vz*inv;
    float cx = sy*dz - sz*dy, cy = sz*dx - sx*dz, cz = sx*dy - sy*dx;
    float cn = sqrtf(cx*cx + cy*cy + cz*cz) + 1e-10f;
    cx /= cn; cy /= cn; cz /= cn;
    float wx = uy*cz - uz*cy, wy = uz*cx - ux*cz, wz = ux*cy - uy*cx;
    frame[(0*3+0)*NE + e] = ux; frame[(1*3+0)*NE + e] = uy; frame[(2*3+0)*NE + e] = uz;
    frame[(0*3+1)*NE + e] = cx; frame[(1*3+1)*NE + e] = cy; frame[(2*3+1)*NE + e] = cz;
    frame[(0*3+2)*NE + e] = wx; frame[(1*3+2)*NE + e] = wy; frame[(2*3+2)*NE + e] = wz;
}

// ---------------------------------------------------------------- rbf chunk (f32, stride KD)
__global__ void k_rbf(const float* __restrict__ dist, const float* __restrict__ rbnd,
                      float* __restrict__ base, int e0, int ec){
    int idx = blockIdx.x * 256 + threadIdx.x;
    int e = idx / NRAD;
    if (e >= ec) return;
    int k = idx - e * NRAD;
    int eg = e0 + e;
    float start = expf(-6.0f);
    float mean  = start + (1.0f - start) * ((float)k / 95.0f);
    float c     = (2.0f / 96.0f) * (1.0f - start);
    float betas = 1.0f / (c * c);
    float t = expf(-dist[eg]) - mean;
    base[(size_t)e * KD + k] = rbnd[eg] * expf(-betas * t * t);
}

// ---------------------------------------------------------------- split-A x bf16-B MFMA GEMM (R14 proven)
__global__ __launch_bounds__(256)
void mgemm(const float* __restrict__ A, int lda,
           const u16* __restrict__ Bhg, int K,
           const float* __restrict__ bias, int act,
           float* __restrict__ C, int ldc,
           int M, int Nn,
           const float* __restrict__ row_scale,
           const float* __restrict__ mulC, int ldm){
    __shared__ u16 Ah[128*40], Al[128*40];
    __shared__ u16 Bh[64*40];
    int tid = threadIdx.x;
    int w = tid >> 6, l = tid & 63;
    int row0 = blockIdx.x * 128, col0 = blockIdx.y * 64;
    f32x4 acc[2][4] = {};
    const int r16 = l & 15, kb = (l >> 4) * 8;

    for (int k0 = 0; k0 < K; k0 += 32){
        if (k0) __syncthreads();
#pragma unroll
        for (int i = 0; i < 4; i++){
            int f = tid + i * 256;
            int r = f >> 3, kq = (f & 7) * 4;
            const float4 v = *(const float4*)(A + (size_t)(row0 + r) * lda + k0 + kq);
            uint2 ph, pl;
            split4(v, ph, pl);
            *(uint2*)&Ah[r*40 + kq] = ph;
            *(uint2*)&Al[r*40 + kq] = pl;
        }
        {
            int bn = tid >> 2, kq = (tid & 3) * 8;
            const size_t gb = (size_t)(col0 + bn) * K + k0 + kq;
            *(short8*)&Bh[bn*40 + kq] = ld8(Bhg + gb);
        }
        __syncthreads();
        short8 ah0 = *(const short8*)&Ah[(w*32      + r16)*40 + kb];
        short8 ah1 = *(const short8*)&Ah[(w*32 + 16 + r16)*40 + kb];
        short8 al0 = *(const short8*)&Al[(w*32      + r16)*40 + kb];
        short8 al1 = *(const short8*)&Al[(w*32 + 16 + r16)*40 + kb];
#pragma unroll
        for (int nf = 0; nf < 4; nf++){
            short8 bhv = *(const short8*)&Bh[(nf*16 + r16)*40 + kb];
            acc[0][nf] = __builtin_amdgcn_mfma_f32_16x16x32_bf16(ah0, bhv, acc[0][nf], 0, 0, 0);
            acc[0][nf] = __builtin_amdgcn_mfma_f32_16x16x32_bf16(al0, bhv, acc[0][nf], 0, 0, 0);
            acc[1][nf] = __builtin_amdgcn_mfma_f32_16x16x32_bf16(ah1, bhv, acc[1][nf], 0, 0, 0);
            acc[1][nf] = __builtin_amdgcn_mfma_f32_16x16x32_bf16(al1, bhv, acc[1][nf], 0, 0, 0);
        }
    }
    int rq = (l >> 4) * 4;
#pragma unroll
    for (int mf = 0; mf < 2; mf++){
#pragma unroll
        for (int nf = 0; nf < 4; nf++){
            int n = col0 + nf*16 + r16;
            float bz = bias ? bias[n] : 0.0f;
#pragma unroll
            for (int reg = 0; reg < 4; reg++){
                int m = row0 + w*32 + mf*16 + rq + reg;
                float v = acc[mf][nf][reg] + bz;
                if (act) v = siluf(v);
                if (row_scale) v *= row_scale[m];
                if (mulC) v *= mulC[(size_t)m * ldm + n];
                C[(size_t)m * ldc + n] = v;
            }
        }
    }
}

// ---------------------------------------------------------------- fused rw-GEMM + dw2-GEMM + scatter (R14 proven)
__global__ __launch_bounds__(256)
void dw2s(const float* __restrict__ hb,
          const float* __restrict__ ewrbf,
          const u16* __restrict__ B1h,
          const u16* __restrict__ B2h,
          const float* __restrict__ rb, const float* __restrict__ db2,
          const float* __restrict__ xh, const float* __restrict__ vec,
          const float* __restrict__ frame, const int* __restrict__ ei,
          float* __restrict__ s, float* __restrict__ vec_acc, int e0){
    __shared__ u16 Ah[128*40], Al[128*40];
    __shared__ u16 Bh[64*40];
    int tid = threadIdx.x;
    int w = tid >> 6, l = tid & 63;
    int row0 = blockIdx.x * 128, col0 = blockIdx.y * 64;
    const int r16 = l & 15, kb = (l >> 4) * 8;
    f32x4 acc1[2][4] = {}, acc2[2][4] = {};

    // phase 2: acc2 = rbf @ rw (K=96, A stride KD)
    for (int k0 = 0; k0 < 96; k0 += 32){
        if (k0) __syncthreads();
#pragma unroll
        for (int i = 0; i < 4; i++){
            int f = tid + i * 256;
            int r = f >> 3, kq = (f & 7) * 4;
            const float4 v = *(const float4*)(ewrbf + (size_t)(row0 + r) * KD + k0 + kq);
            uint2 ph, pl;
            split4(v, ph, pl);
            *(uint2*)&Ah[r*40 + kq] = ph;
            *(uint2*)&Al[r*40 + kq] = pl;
        }
        {
            int bn = tid >> 2, kq = (tid & 3) * 8;
            const size_t gb = (size_t)(col0 + bn) * 96 + k0 + kq;
            *(short8*)&Bh[bn*40 + kq] = ld8(B2h + gb);
        }
        __syncthreads();
        short8 ah0 = *(const short8*)&Ah[(w*32      + r16)*40 + kb];
        short8 ah1 = *(const short8*)&Ah[(w*32 + 16 + r16)*40 + kb];
        short8 al0 = *(const short8*)&Al[(w*32      + r16)*40 + kb];
        short8 al1 = *(const short8*)&Al[(w*32 + 16 + r16)*40 + kb];
#pragma unroll
        for (int nf = 0; nf < 4; nf++){
            short8 bhv = *(const short8*)&Bh[(nf*16 + r16)*40 + kb];
            acc2[0][nf] = __builtin_amdgcn_mfma_f32_16x16x32_bf16(ah0, bhv, acc2[0][nf], 0, 0, 0);
            acc2[0][nf] = __builtin_amdgcn_mfma_f32_16x16x32_bf16(al0, bhv, acc2[0][nf], 0, 0, 0);
            acc2[1][nf] = __builtin_amdgcn_mfma_f32_16x16x32_bf16(ah1, bhv, acc2[1][nf], 0, 0, 0);
            acc2[1][nf] = __builtin_amdgcn_mfma_f32_16x16x32_bf16(al1, bhv, acc2[1][nf], 0, 0, 0);
        }
    }
    // phase 1: acc1 = hbuf @ dw2 (K=384, A stride H3)
    for (int k0 = 0; k0 < H3; k0 += 32){
        __syncthreads();
#pragma unroll
        for (int i = 0; i < 4; i++){
            int f = tid + i * 256;
            int r = f >> 3, kq = (f & 7) * 4;
            const float4 v = *(const float4*)(hb + (size_t)(row0 + r) * H3 + k0 + kq);
            uint2 ph, pl;
            split4(v, ph, pl);
            *(uint2*)&Ah[r*40 + kq] = ph;
            *(uint2*)&Al[r*40 + kq] = pl;
        }
        {
            int bn = tid >> 2, kq = (tid & 3) * 8;
            const size_t gb = (size_t)(col0 + bn) * H3 + k0 + kq;
            *(short8*)&Bh[bn*40 + kq] = ld8(B1h + gb);
        }
        __syncthreads();
        short8 ah0 = *(const short8*)&Ah[(w*32      + r16)*40 + kb];
        short8 ah1 = *(const short8*)&Ah[(w*32 + 16 + r16)*40 + kb];
        short8 al0 = *(const short8*)&Al[(w*32      + r16)*40 + kb];
        short8 al1 = *(const short8*)&Al[(w*32 + 16 + r16)*40 + kb];
#pragma unroll
        for (int nf = 0; nf < 4; nf++){
            short8 bhv = *(const short8*)&Bh[(nf*16 + r16)*40 + kb];
            acc1[0][nf] = __builtin_amdgcn_mfma_f32_16x16x32_bf16(ah0, bhv, acc1[0][nf], 0, 0, 0);
            acc1[0][nf] = __builtin_amdgcn_mfma_f32_16x16x32_bf16(al0, bhv, acc1[0][nf], 0, 0, 0);
            acc1[1][nf] = __builtin_amdgcn_mfma_f32_16x16x32_bf16(ah1, bhv, acc1[1][nf], 0, 0, 0);
            acc1[1][nf] = __builtin_amdgcn_mfma_f32_16x16x32_bf16(al1, bhv, acc1[1][nf], 0, 0, 0);
        }
    }
    // epilogue: rbfh -> scatter
    int rq = (l >> 4) * 4;
    int br = col0 >> 7;          // 0,1,2 (uniform per block)
    int ho = col0 & 127;         // 0 or 64
#pragma unroll
    for (int mf = 0; mf < 2; mf++){
#pragma unroll
        for (int reg = 0; reg < 4; reg++){
            int m  = row0 + w*32 + mf*16 + rq + reg;
            int eg = e0 + m;
            int si = ei[eg], di = ei[NE + eg];
            float df0 = 0.f, df1 = 0.f, df2 = 0.f;
            if (br == 2){
                df0 = frame[0*NE + eg];
                df1 = frame[3*NE + eg];
                df2 = frame[6*NE + eg];
            }
#pragma unroll
            for (int nf = 0; nf < 4; nf++){
                int n = col0 + nf*16 + r16;
                int h = ho + nf*16 + r16;
                float v  = (acc2[mf][nf][reg] + rb[n]) * (acc1[mf][nf][reg] + db2[n]);
                float xv = xh[(size_t)si * H3 + n];
                if (br == 0){
                    atomicAdd(&s[(size_t)di * HD + h], xv * v);
                } else if (br == 1){
                    float m2 = xv * v * 0.5773502691896258f;
                    size_t sb = (size_t)si * H3, db = (size_t)di * H3;
#pragma unroll
                    for (int c = 0; c < 3; c++)
                        atomicAdd(&vec_acc[db + c*HD + h],
                                  vec[sb + c*HD + h] * m2 * 0.08838834764831845f);
                } else {
                    float m3 = xv * v * 0.08838834764831845f;
                    size_t db = (size_t)di * H3;
                    atomicAdd(&vec_acc[db + 0*HD + h], m3 * df0);
                    atomicAdd(&vec_acc[db + 1*HD + h], m3 * df1);
                    atomicAdd(&vec_acc[db + 2*HD + h], m3 * df2);
                }
            }
        }
    }
}

struct WT { u16* h; };

static void gemm(hipStream_t st, const float* A, int lda, WT B,
                 const float* bias, float* C, int ldc, size_t M, int K, int Nn,
                 int act, const float* rs, const float* mul, int ldm){
    dim3 g((unsigned)(M / 128), (unsigned)(Nn / 64)), b(256);
    mgemm<<<g, b, 0, st>>>(A, lda, B.h, K, bias, act, C, ldc, (int)M, Nn, rs, mul, ldm);
}

// ---------------------------------------------------------------- s[dst] += rh * sn[src]
__global__ void k_scatter_s(const float* __restrict__ rh, const float* __restrict__ sn,
                            const int* __restrict__ ei, float* __restrict__ s, int e0, int ec,
                            long long stride){
    int idx = blockIdx.x * 256 + threadIdx.x;
    int e = idx >> 7, h = idx & 127;
    if (e >= ec) return;
    int eg = e0 + e;
    int si = ei[eg], di = ei[NE + eg];
    atomicAdd(&s[(size_t)di * HD + h], rh[(size_t)e * stride + h] * sn[(size_t)si * HD + h]);
}

// ---------------------------------------------------------------- S_ij[dst,c,h] += rh*diff_c*s1[src,h]
__global__ void k_scatter_msgv(const float* __restrict__ rh, const float* __restrict__ s1,
                               const float* __restrict__ frame, const int* __restrict__ ei,
                               float* __restrict__ S_ij, int e0, int ec){
    int idx = blockIdx.x * 256 + threadIdx.x;
    int e = idx >> 7, h = idx & 127;
    if (e >= ec) return;
    int eg = e0 + e;
    int si = ei[eg], di = ei[NE + eg];
    float mv = rh[(size_t)e * KD + h] * s1[(size_t)si * HD + h];
    size_t db = (size_t)di * H3;
#pragma unroll
    for (int c = 0; c < 3; c++){
        float df = frame[(c*3 + 0) * NE + eg];
        atomicAdd(&S_ij[db + c * HD + h], mv * df);
    }
}

// ---------------------------------------------------------------- scalarize -> base[:,0:256]
__global__ void k_scalarize(const float* __restrict__ S_ij, const float* __restrict__ frame,
                            const float* __restrict__ rbnd, const int* __restrict__ ei,
                            const float* __restrict__ w1, const float* __restrict__ b1,
                            const float* __restrict__ w2, const float* __restrict__ b2v,
                            float* __restrict__ base, int e0){
    int e = blockIdx.x, h = threadIdx.x;   // 128 threads
    int eg = e0 + e;
    int si = ei[eg], di = ei[NE + eg];
    float fr[9];
#pragma unroll
    for (int i = 0; i < 9; i++) fr[i] = frame[i * NE + eg];
    float rb = rbnd[eg];
    float b2 = b2v[0];
#pragma unroll
    for (int g = 0; g < 2; g++){
        int node = g ? di : si;
        float S0 = S_ij[(size_t)node * H3 + h];
        float S1 = S_ij[(size_t)node * H3 + 128 + h];
        float S2 = S_ij[(size_t)node * H3 + 256 + h];
        float p0 = fr[0]*S0 + fr[3]*S1 + fr[6]*S2;
        float p1 = fabsf(fr[1]*S0 + fr[4]*S1 + fr[7]*S2);
        float p2 = fr[2]*S0 + fr[5]*S1 + fr[8]*S2;
        float o = b2 + p0;
#pragma unroll
        for (int j = 0; j < 32; j++){
            float hh = siluf(p0 * w1[j] + p1 * w1[32 + j] + p2 * w1[64 + j] + b1[j]);
            o += hh * w2[j];
        }
        base[(size_t)e * KD + g * 128 + h] = o * rb;
    }
}

// ---------------------------------------------------------------- fused: vec += vec_acc (all), s *= 1/sqrt2 (c==0 lanes)
__global__ void k_scale_vecadd(float* __restrict__ s, float* __restrict__ vec,
                               const float* __restrict__ vec_acc){
    int i = blockIdx.x * 256 + threadIdx.x;   // over NN*H3
    vec[i] += vec_acc[i];
    int n = i / H3, r = i - n * H3;
    if (r < HD) s[(size_t)n * HD + r] *= 0.7071067811865476f;
}

// ---------------------------------------------------------------- v-features
__global__ void k_vfeat(const float* __restrict__ vp, const float* __restrict__ s,
                        float* __restrict__ t256, float* __restrict__ vdot){
    int idx = blockIdx.x * 256 + threadIdx.x;
    int n = idx >> 7, h = idx & 127;
    float a = 0.f, b = 0.f;
#pragma unroll
    for (int c = 0; c < 3; c++){
        float v1 = vp[(size_t)(n*3 + c) * 256 + h];
        float v2 = vp[(size_t)(n*3 + c) * 256 + 128 + h];
        a += v1 * v1;
        b += v1 * v2;
    }
    t256[(size_t)n * 256 + 128 + h] = sqrtf(a + 1e-10f);
    vdot[idx] = b * 0.08838834764831845f;
    t256[(size_t)n * 256 + h] = s[idx];
}

// ---------------------------------------------------------------- fused: vec update (all) + s update (c==0 lanes)
__global__ void k_upd(float* __restrict__ s, float* __restrict__ vec,
                      const float* __restrict__ xvh, const float* __restrict__ vp,
                      const float* __restrict__ vdot){
    int idx = blockIdx.x * 256 + threadIdx.x;   // over NN*H3
    int n = idx / H3;
    int r = idx - n * H3;
    int c = r >> 7, h = r & 127;
    vec[idx] += xvh[(size_t)n * H3 + 256 + h] * vp[(size_t)(n*3 + c) * 256 + 128 + h];
    if (c == 0){
        size_t si = (size_t)n * HD + h;
        s[si] += (xvh[(size_t)n * H3 + h] + xvh[(size_t)n * H3 + 128 + h]
                  + vdot[si]) * 0.7071067811865476f;
    }
}

// ---------------------------------------------------------------- final readout
__global__ void k_final(const float* __restrict__ s, const float* __restrict__ lw,
                        const float* __restrict__ lb, const int* __restrict__ batch,
                        float* __restrict__ out){
    int n = blockIdx.x, t = threadIdx.x;   // 64 threads
    float v = s[(size_t)n * HD + t] * lw[t] + s[(size_t)n * HD + 64 + t] * lw[64 + t];
    v = wsum(v);
    if (t == 0) atomicAdd(&out[batch[n]], v + lb[0]);
}

// ================================================================ host
extern "C" void kernel_launch(void* const* d_in, const int* in_sizes, int n_in,
                              void* d_out, int out_size, void* d_ws, size_t ws_size,
                              hipStream_t stream){
    const float* pos      = (const float*)d_in[0];
    const float* z_emb_w  = (const float*)d_in[1];
    const float* ne_emb_w = (const float*)d_in[2];
    const float* rl_w1    = (const float*)d_in[3];
    const float* rl_b1    = (const float*)d_in[4];
    const float* rl_w2    = (const float*)d_in[5];
    const float* rl_b2    = (const float*)d_in[6];
    const float* sv_w     = (const float*)d_in[7];
    const float* sv_b     = (const float*)d_in[8];
    const float* lin_w1   = (const float*)d_in[9];
    const float* lin_b1   = (const float*)d_in[10];
    const float* lin_w2   = (const float*)d_in[11];
    const float* lin_b2   = (const float*)d_in[12];
    const float* mp_ln_g  = (const float*)d_in[13];
    const float* mp_ln_b  = (const float*)d_in[14];
    const float* mp_xw1   = (const float*)d_in[15];
    const float* mp_xb1   = (const float*)d_in[16];
    const float* mp_xw2   = (const float*)d_in[17];
    const float* mp_xb2   = (const float*)d_in[18];
    const float* mp_rw    = (const float*)d_in[19];
    const float* mp_rb    = (const float*)d_in[20];
    const float* mp_dw1   = (const float*)d_in[21];
    const float* mp_db1   = (const float*)d_in[22];
    const float* mp_dw2   = (const float*)d_in[23];
    const float* mp_db2   = (const float*)d_in[24];
    const float* ft_vw    = (const float*)d_in[25];
    const float* ft_xw1   = (const float*)d_in[26];
    const float* ft_xb1   = (const float*)d_in[27];
    const float* ft_xw2   = (const float*)d_in[28];
    const float* ft_xb2   = (const float*)d_in[29];
    const float* last_w   = (const float*)d_in[30];
    const float* last_b   = (const float*)d_in[31];
    const int*   z        = (const int*)d_in[32];
    const int*   ei       = (const int*)d_in[33];
    const int*   batch    = (const int*)d_in[34];
    float* out = (float*)d_out;
    (void)in_sizes; (void)n_in; (void)out_size;

    float* ws = (float*)d_ws;
    size_t off = 0;
    auto alloc = [&](size_t nf){ float* p = ws + off; off += (nf + 63) & ~(size_t)63; return p; };

    // ---- fixed node/geometry buffers
    float* s       = alloc((size_t)NN * HD);
    float* sn      = alloc((size_t)NN * HD);
    float* s1      = alloc((size_t)NN * HD);
    float* tA      = alloc((size_t)NN * HD);
    float* vdot    = alloc((size_t)NN * HD);
    float* vec     = alloc((size_t)NN * H3);
    float* vec_acc = alloc((size_t)NN * H3);
    float* S_ij    = alloc((size_t)NN * H3);
    float* xh      = alloc((size_t)NN * H3);
    float* vp      = alloc((size_t)NN * 3 * 256);
    float* dist    = alloc((size_t)NE);
    float* rbnd    = alloc((size_t)NE);
    float* frame   = alloc((size_t)NE * 9);
    float* t256    = sn;   // alias: (N,256) over sn+s1 (layer phase only; sn/s1 prologue-only)

    // ---- weight bf16 plane arena (transposed)
    const size_t WELEMS = 45056 + 2 * 548864;
    u16* wcur = (u16*)alloc((WELEMS + 1) / 2);
    auto wsplit = [&](const float* src, int K, int N)->WT{
        WT r; r.h = wcur; wcur += (size_t)K * N;
        k_wsplit<<<(unsigned)(((size_t)K * N + 255) / 256), 256, 0, stream>>>(src, r.h, K, N);
        return r;
    };
    WT W_rl1 = wsplit(rl_w1, NRAD, HD);
    WT W_rl2 = wsplit(rl_w2, HD, HD);
    WT W_sv  = wsplit(sv_w, HD, HD);
    WT W_xw1[2], W_xw2[2], W_rw[2], W_dw1[2], W_dw2[2], W_vw[2], W_fx1[2], W_fx2[2];
    for (int l = 0; l < 2; l++){
        W_xw1[l] = wsplit(mp_xw1 + (size_t)l * HD * HD, HD, HD);
        W_xw2[l] = wsplit(mp_xw2 + (size_t)l * HD * H3, HD, H3);
        W_rw[l]  = wsplit(mp_rw  + (size_t)l * NRAD * H3, NRAD, H3);
        W_dw1[l] = wsplit(mp_dw1 + (size_t)l * KD * H3, KD, H3);
        W_dw2[l] = wsplit(mp_dw2 + (size_t)l * H3 * H3, H3, H3);
        W_vw[l]  = wsplit(ft_vw  + (size_t)l * HD * 256, HD, 256);
        W_fx1[l] = wsplit(ft_xw1 + (size_t)l * 256 * HD, 256, HD);
        W_fx2[l] = wsplit(ft_xw2 + (size_t)l * HD * H3, HD, H3);
    }

    // ---- adaptive edge scratch (CE multiple of 128; L3-residency cap)
    size_t availF = ws_size / sizeof(float);
    size_t rem = (availF > off + 1024) ? (availF - off - 1024) : 0;
    const size_t EWF = (size_t)NE * KD;
    bool persist;
    size_t CE;
    float* ew  = nullptr;
    float* ewc = nullptr;
    if (rem >= EWF + 128 * 384 + 256){
        persist = true;
        ew = alloc(EWF);
        rem = availF - off - 1024;
        size_t ce = rem / (size_t)H3;
        CE = ce & ~(size_t)127;
        if (CE < 128) CE = 128;
        if (CE > NE) CE = NE;
    } else {
        persist = false;
        size_t ce = rem / ((size_t)KD + (size_t)H3);
        CE = ce & ~(size_t)127;
        if (CE < 128) CE = 128;
        if (CE > NE) CE = NE;
    }
    if (CE > 32768) CE = 32768;
    if (!persist) ewc = alloc(CE * KD);
    float* hbuf = alloc(CE * (size_t)H3);

    auto build_rh = [&](size_t e0, size_t ec, float* base){
        k_rbf<<<(unsigned)((ec * NRAD) / 256), 256, 0, stream>>>(dist, rbnd, base + 384, (int)e0, (int)ec);
        gemm(stream, base + 384, KD, W_rl1, rl_b1, hbuf, HD, ec, NRAD, HD, 1, nullptr, nullptr, 0);
        gemm(stream, hbuf, HD, W_rl2, rl_b2, base + 256, KD, ec, HD, HD, 0, rbnd + e0, nullptr, 0);
    };

    // ---- prologue
    k_fill<<<1, 64, 0, stream>>>(out, 0.f, NG);
    k_node_embed<<<NN, 64, 0, stream>>>(z_emb_w, ne_emb_w, z, s, sn);
    k_edge_geom<<<NE / 256, 256, 0, stream>>>(pos, ei, dist, rbnd, frame);

    if (persist){
        for (size_t e0 = 0; e0 < NE; e0 += CE){
            size_t ec = (NE - e0 < CE) ? (NE - e0) : CE;
            build_rh(e0, ec, ew + e0 * KD);
        }
        // single full-NE scatter (fewer launches, no chunk serialization)
        k_scatter_s<<<(unsigned)(((size_t)NE * HD) / 256), 256, 0, stream>>>(ew + 256, sn, ei, s, 0, NE, KD);
    } else {
        for (size_t e0 = 0; e0 < NE; e0 += CE){
            size_t ec = (NE - e0 < CE) ? (NE - e0) : CE;
            build_rh(e0, ec, ewc);
            k_scatter_s<<<(unsigned)((ec * HD) / 256), 256, 0, stream>>>(ewc + 256, sn, ei, s, (int)e0, (int)ec, KD);
        }
    }

    gemm(stream, s, HD, W_sv, sv_b, tA, HD, NN, HD, HD, 0, nullptr, nullptr, 0);
    k_ln_silu<<<NN, 64, 0, stream>>>(tA, s1);

    k_fill<<<(NN * H3) / 256, 256, 0, stream>>>(S_ij, 0.f, NN * H3);
    if (persist){
        k_scatter_msgv<<<(unsigned)(((size_t)NE * HD) / 256), 256, 0, stream>>>(ew + 256, s1, frame, ei, S_ij, 0, NE);
        k_scalarize<<<NE, 128, 0, stream>>>(S_ij, frame, rbnd, ei, lin_w1, lin_b1, lin_w2, lin_b2, ew, 0);
    } else {
        for (size_t e0 = 0; e0 < NE; e0 += CE){
            size_t ec = (NE - e0 < CE) ? (NE - e0) : CE;
            build_rh(e0, ec, ewc);
            k_scatter_msgv<<<(unsigned)((ec * HD) / 256), 256, 0, stream>>>(ewc + 256, s1, frame, ei, S_ij, (int)e0, (int)ec);
        }
    }

    k_fill<<<(NN * H3) / 256, 256, 0, stream>>>(vec, 0.f, NN * H3);

    // ---- layer loop
    for (int l = 0; l < 2; l++){
        k_ln_aff<<<NN, 64, 0, stream>>>(s, mp_ln_g + l * HD, mp_ln_b + l * HD, tA);
        gemm(stream, tA, HD, W_xw1[l], mp_xb1 + l * HD, vdot, HD, NN, HD, HD, 1, nullptr, nullptr, 0);
        gemm(stream, vdot, HD, W_xw2[l], mp_xb2 + l * H3, xh, H3, NN, HD, H3, 0, nullptr, nullptr, 0);

        k_fill<<<(NN * H3) / 256, 256, 0, stream>>>(vec_acc, 0.f, NN * H3);

        for (size_t e0 = 0; e0 < NE; e0 += CE){
            size_t ec = (NE - e0 < CE) ? (NE - e0) : CE;
            float* base = persist ? (ew + e0 * KD) : ewc;
            if (!persist){
                build_rh(e0, ec, base);
                k_scalarize<<<(unsigned)ec, 128, 0, stream>>>(S_ij, frame, rbnd, ei, lin_w1, lin_b1, lin_w2, lin_b2, base, (int)e0);
            }
            gemm(stream, base, KD, W_dw1[l], mp_db1 + l * H3, hbuf, H3, ec, KD, H3, 1, nullptr, nullptr, 0);
            dim3 g((unsigned)(ec / 128), 6);
            dw2s<<<g, 256, 0, stream>>>(hbuf, base + 384,
                                        W_dw2[l].h, W_rw[l].h,
                                        mp_rb + l * H3, mp_db2 + l * H3,
                                        xh, vec, frame, ei, s, vec_acc, (int)e0);
        }
        k_scale_vecadd<<<(NN * H3) / 256, 256, 0, stream>>>(s, vec, vec_acc);

        gemm(stream, vec, HD, W_vw[l], nullptr, vp, 256, (size_t)NN * 3, HD, 256, 0, nullptr, nullptr, 0);
        k_vfeat<<<(NN * HD) / 256, 256, 0, stream>>>(vp, s, t256, vdot);

        gemm(stream, t256, 256, W_fx1[l], ft_xb1 + l * HD, tA, HD, NN, 256, HD, 1, nullptr, nullptr, 0);
        gemm(stream, tA, HD, W_fx2[l], ft_xb2 + l * H3, xh, H3, NN, HD, H3, 0, nullptr, nullptr, 0);

        k_upd<<<(NN * H3) / 256, 256, 0, stream>>>(s, vec, xh, vp, vdot);
    }

    // ---- readout
    k_final<<<NN, 64, 0, stream>>>(s, last_w, last_b, batch, out);
}